// Round 5
// baseline (6727.572 us; speedup 1.0000x reference)
//
#include <hip/hip_runtime.h>
#include <math.h>

#define SEQ 200

typedef float f32x4 __attribute__((ext_vector_type(4)));
typedef short bf16x8 __attribute__((ext_vector_type(8)));

__device__ __forceinline__ float sigmoidf_(float x) { return 1.0f / (1.0f + __expf(-x)); }

__device__ __forceinline__ unsigned short bf16_rn(float v) {
    unsigned x = __float_as_uint(v);
    unsigned r = x + 0x7FFFu + ((x >> 16) & 1u);
    return (unsigned short)(r >> 16);
}
__device__ __forceinline__ float bf16_to_f(unsigned short h) {
    return __uint_as_float(((unsigned)h) << 16);
}
__device__ __forceinline__ void cvt_hl(float v, unsigned short& h, unsigned short& l) {
    h = bf16_rn(v);
    l = bf16_rn(v - bf16_to_f(h));
}

// ---------------- W_out transpose: WoT[90][256] (rows 88,89 used for pred) ----
__global__ void transpose_wout(const float* __restrict__ W_out, float* __restrict__ WoT) {
    int c = blockIdx.x;      // 0..89
    int k = threadIdx.x;     // 0..255
    WoT[c * 256 + k] = W_out[k * 90 + c];
}

// ---------------- Wt prep: Wt_h/Wt_l[1152 rc][448 k] bf16 ----------------
// rc = hj*144 + lc.
//  lc <128 : gates, gcol = (lc>>5)*256 + hj*32 + (lc&31); k: 0-174 W_ih, 176-431 W_hh
//  lc 128..139 : out cols, col = hj*12+(lc-128) (<90); k 176-431 = W_out rows
//  else zero
__global__ void prep_wt(const float* __restrict__ W_ih, const float* __restrict__ W_hh,
                        const float* __restrict__ W_out,
                        unsigned short* __restrict__ Wt_h, unsigned short* __restrict__ Wt_l) {
    int rc = blockIdx.x;
    int hj = rc / 144, lc = rc - hj * 144;
    for (int k = threadIdx.x; k < 448; k += 256) {
        float v = 0.f;
        if (lc < 128) {
            int gcol = (lc >> 5) * 256 + hj * 32 + (lc & 31);
            if (k < 175) v = W_ih[(size_t)k * 1024 + gcol];
            else if (k >= 176 && k < 432) v = W_hh[(size_t)(k - 176) * 1024 + gcol];
        } else if (lc < 140) {
            int col = hj * 12 + (lc - 128);
            if (col < 90 && k >= 176 && k < 432) v = W_out[(size_t)(k - 176) * 90 + col];
        }
        unsigned short h, l; cvt_hl(v, h, l);
        Wt_h[(size_t)rc * 448 + k] = h;
        Wt_l[(size_t)rc * 448 + k] = l;
    }
}

// ---------------- Encoder -> xin_h[t][b][176] bf16 ----------------
__global__ __launch_bounds__(256) void enc_kernel(
    const float* __restrict__ coords,
    const float* __restrict__ W_e1, const float* __restrict__ b_e1,
    const float* __restrict__ W_e2, const float* __restrict__ b_e2,
    unsigned short* __restrict__ xin_h)
{
    __shared__ float C[64][89];
    __shared__ float H[64][2][65];
    __shared__ float W2[64][64];
    __shared__ float O[128][65];   // padded 65 to kill column-write bank conflicts

    int t  = blockIdx.x >> 4;
    int bc = blockIdx.x & 15;
    int tid = threadIdx.x;

    for (int idx = tid; idx < 64 * 88; idx += 256) {
        int bl = idx / 88, j = idx - bl * 88;
        C[bl][j] = coords[((size_t)(bc * 64 + bl) * SEQ + t) * 88 + j];
    }
    for (int idx = tid; idx < 64 * 64; idx += 256)
        W2[idx >> 6][idx & 63] = W_e2[idx];
    __syncthreads();

    {
        int b  = tid >> 2;
        int cq = (tid & 3) * 16;
        float w0[16], w1[16], bb[16];
#pragma unroll
        for (int c = 0; c < 16; c++) { w0[c] = W_e1[cq + c]; w1[c] = W_e1[64 + cq + c]; bb[c] = b_e1[cq + c]; }
        for (int tm = 0; tm < 2; tm++) {
            float acc[16];
#pragma unroll
            for (int c = 0; c < 16; c++) acc[c] = 0.f;
            for (int p = 0; p < 11; p++) {
                float x = C[b][(tm * 11 + p) * 4];
                float y = C[b][(tm * 11 + p) * 4 + 1];
#pragma unroll
                for (int c = 0; c < 16; c++) {
                    float h = fmaf(x, w0[c], fmaf(y, w1[c], bb[c]));
                    acc[c] += fmaxf(h, 0.f);
                }
            }
#pragma unroll
            for (int c = 0; c < 16; c++) H[b][tm][cq + c] = acc[c] * (1.0f / 11.0f);
        }
    }
    __syncthreads();

    {
        int b  = tid >> 2;
        int tm = (tid >> 1) & 1;
        int ch = (tid & 1) * 32;
        float acc[32];
#pragma unroll
        for (int c = 0; c < 32; c++) acc[c] = 0.f;
        for (int k = 0; k < 64; k++) {
            float h = H[b][tm][k];
#pragma unroll
            for (int c = 0; c < 32; c++) acc[c] = fmaf(h, W2[k][ch + c], acc[c]);
        }
#pragma unroll
        for (int c = 0; c < 32; c++) O[tm * 64 + ch + c][b] = acc[c] + b_e2[ch + c];
    }
    __syncthreads();

    unsigned short* xrow = xin_h + ((size_t)t * 1024 + bc * 64) * 176;
    for (int idx = tid; idx < 64 * 22; idx += 256) {
        int bl = idx / 22, oct = idx - bl * 22;
        unsigned short hs[8];
#pragma unroll
        for (int e = 0; e < 8; e++) {
            int k = oct * 8 + e;
            float v;
            if (k < 44)       v = C[bl][(k >> 1) * 4 + (k & 1)];
            else if (k < 172) v = O[k - 44][bl];
            else              v = 0.f;
            hs[e] = bf16_rn(v);
        }
        uint4 pk;
        pk.x = (unsigned)hs[0] | ((unsigned)hs[1] << 16);
        pk.y = (unsigned)hs[2] | ((unsigned)hs[3] << 16);
        pk.z = (unsigned)hs[4] | ((unsigned)hs[5] << 16);
        pk.w = (unsigned)hs[6] | ((unsigned)hs[7] << 16);
        *(uint4*)(xrow + (size_t)bl * 176 + oct * 8) = pk;
    }
}

// ---------------- Per-step kernel (MFMA, out folded into B) ----------------
// grid 256: bi = blockIdx.x&31 (32-batch tile), hj = blockIdx.x>>5.
// B-ext = 144 cols: 128 gates + 16 out-tile (wave 0). lo-terms only for ks>=5 (hx rows).
__global__ __launch_bounds__(256) void step_kernel(
    int t,
    const unsigned short* __restrict__ xin_h,
    const unsigned short* __restrict__ hxh_in, const unsigned short* __restrict__ hxl_in,
    unsigned short* __restrict__ hxh_out, unsigned short* __restrict__ hxl_out,
    float* __restrict__ cx,
    const unsigned short* __restrict__ Wt_h, const unsigned short* __restrict__ Wt_l,
    const float* __restrict__ b_ih, const float* __restrict__ b_hh,
    const float* __restrict__ WoT, const float* __restrict__ b_out,
    const float* __restrict__ pitch, float* __restrict__ d_out)
{
    __shared__ unsigned short AH[32 * 456];        // 29184 B
    __shared__ unsigned short AL[32 * 456];        // 29184 B
    __shared__ unsigned short BB[2][2][144 * 40];  // 46080 B
    __shared__ float U[144 * 33];                  // 19008 B: Wo2+pred scratch / G gates

    int tid = threadIdx.x;
    int bi = blockIdx.x & 31, hj = blockIdx.x >> 5;
    int bg0 = bi * 32;
    int tx = (t < SEQ) ? t : SEQ - 1;   // t==SEQ: stage stale x (finite), gates discarded

    // ---- stage ----
    {
        const unsigned short* xr = xin_h + ((size_t)tx * 1024 + bg0) * 176;
        for (int idx = tid; idx < 32 * 22; idx += 256) {       // AH k 0..175
            int b = idx / 22, oct = idx - b * 22;
            *(uint4*)&AH[b * 456 + oct * 8] = *(const uint4*)(xr + (size_t)b * 176 + oct * 8);
        }
        for (int idx = tid; idx < 32 * 32; idx += 256) {       // k 176..431 (hx h/l)
            int b = idx >> 5, oct = idx & 31;
            *(uint4*)&AH[b * 456 + 176 + oct * 8] =
                *(const uint4*)(hxh_in + (size_t)(bg0 + b) * 256 + oct * 8);
            *(uint4*)&AL[b * 456 + 176 + oct * 8] =
                *(const uint4*)(hxl_in + (size_t)(bg0 + b) * 256 + oct * 8);
        }
        for (int idx = tid; idx < 64; idx += 256) {            // zero tails
            int b = idx >> 1, h8 = (idx & 1) * 8;
            *(uint4*)&AH[b * 456 + 432 + h8] = make_uint4(0, 0, 0, 0);
            *(uint4*)&AL[b * 456 + 432 + h8] = make_uint4(0, 0, 0, 0);
            *(uint4*)&AL[b * 456 + 160 + h8] = make_uint4(0, 0, 0, 0);  // AL k 160..175
        }
        // B chunk ks=0 (hi only; lo not needed until ks=5)
        const unsigned short* wbh0 = Wt_h + (size_t)(hj * 144) * 448;
        for (int idx = tid; idx < 576; idx += 256) {
            int c = idx >> 2, oct = idx & 3;
            *(uint4*)&BB[0][0][c * 40 + oct * 8] = *(const uint4*)(wbh0 + (size_t)c * 448 + oct * 8);
        }
        // Wo2 (pred cols 88,89 over k) -> U[0..511]
        for (int idx = tid; idx < 512; idx += 256)
            U[idx] = WoT[88 * 256 + idx];
    }
    __syncthreads();

    // ---- pred partials: pred = (hxh+hxl) . Wo2, fp32 ----
    {
        int b = tid & 31, kq = tid >> 5;
        float p0 = 0.f, p1 = 0.f;
        if (t > 0) {
#pragma unroll
            for (int kk = 0; kk < 4; kk++) {
                uint4 vh = *(const uint4*)&AH[b * 456 + 176 + kq * 32 + kk * 8];
                uint4 vl = *(const uint4*)&AL[b * 456 + 176 + kq * 32 + kk * 8];
                unsigned ph[4] = {vh.x, vh.y, vh.z, vh.w};
                unsigned pl[4] = {vl.x, vl.y, vl.z, vl.w};
#pragma unroll
                for (int e = 0; e < 4; e++) {
                    int k = kq * 32 + kk * 8 + e * 2;
                    float x0 = bf16_to_f((unsigned short)(ph[e] & 0xFFFFu)) +
                               bf16_to_f((unsigned short)(pl[e] & 0xFFFFu));
                    float x1 = bf16_to_f((unsigned short)(ph[e] >> 16)) +
                               bf16_to_f((unsigned short)(pl[e] >> 16));
                    p0 = fmaf(x0, U[k], p0);       p0 = fmaf(x1, U[k + 1], p0);
                    p1 = fmaf(x0, U[256 + k], p1); p1 = fmaf(x1, U[256 + k + 1], p1);
                }
            }
        }
        U[512 + tid * 2]     = p0;
        U[512 + tid * 2 + 1] = p1;
    }
    __syncthreads();
    if (tid < 32) {
        int b = tid;
        float p0 = 0.f, p1 = 0.f;
#pragma unroll
        for (int kq = 0; kq < 8; kq++) {
            p0 += U[512 + (kq * 32 + b) * 2];
            p1 += U[512 + (kq * 32 + b) * 2 + 1];
        }
        if (t > 0) { p0 = (p0 + b_out[88]) * pitch[0]; p1 = (p1 + b_out[89]) * pitch[1]; }
        else       { p0 = 0.f; p1 = 0.f; }
        float m = 1e30f;
#pragma unroll
        for (int p = 0; p < 22; p++) {
            float px = bf16_to_f(AH[b * 456 + 2 * p]);
            float py = bf16_to_f(AH[b * 456 + 2 * p + 1]);
            float dx = p0 - px, dy = p1 - py;
            m = fminf(m, fmaf(dx, dx, dy * dy));
        }
        unsigned short h, l;
        cvt_hl(sqrtf(m), h, l); AH[b * 456 + 172] = h; AL[b * 456 + 172] = l;
        cvt_hl(p0, h, l);       AH[b * 456 + 173] = h; AL[b * 456 + 173] = l;
        cvt_hl(p1, h, l);       AH[b * 456 + 174] = h; AL[b * 456 + 174] = l;
    }
    __syncthreads();

    // ---- MFMA K-loop: 14 x K=32; lo-terms + out-tile only for ks>=5 ----
    {
        int l = tid & 63, w = tid >> 6;
        int lr = l & 15, qa = l >> 4;
        const unsigned short* wbh = Wt_h + (size_t)(hj * 144) * 448;
        const unsigned short* wbl = Wt_l + (size_t)(hj * 144) * 448;

        f32x4 acc[2][2];
        f32x4 acce[2];
#pragma unroll
        for (int ct = 0; ct < 2; ct++)
#pragma unroll
            for (int mt = 0; mt < 2; mt++) acc[ct][mt] = (f32x4){0.f, 0.f, 0.f, 0.f};
#pragma unroll
        for (int mt = 0; mt < 2; mt++) acce[mt] = (f32x4){0.f, 0.f, 0.f, 0.f};

        uint4 bregH[3], bregL[3];
        for (int ks = 0; ks < 14; ks++) {
            int cur = ks & 1;
            bool lo_now = (ks >= 5);
            bool lo_nxt = (ks >= 4);
            if (ks < 13) {
                int ko = (ks + 1) * 32;
#pragma unroll
                for (int it = 0; it < 3; it++) {
                    int idx = tid + it * 256;
                    if (idx < 576) {
                        int c = idx >> 2, oct = idx & 3;
                        bregH[it] = *(const uint4*)(wbh + (size_t)c * 448 + ko + oct * 8);
                        if (lo_nxt)
                            bregL[it] = *(const uint4*)(wbl + (size_t)c * 448 + ko + oct * 8);
                    }
                }
            }
            bf16x8 ah[2], al[2];
#pragma unroll
            for (int mt = 0; mt < 2; mt++)
                ah[mt] = *(const bf16x8*)&AH[(mt * 16 + lr) * 456 + ks * 32 + qa * 8];
            if (lo_now) {
#pragma unroll
                for (int mt = 0; mt < 2; mt++)
                    al[mt] = *(const bf16x8*)&AL[(mt * 16 + lr) * 456 + ks * 32 + qa * 8];
            }
#pragma unroll
            for (int ct = 0; ct < 2; ct++) {
                bf16x8 bh = *(const bf16x8*)&BB[cur][0][(w * 32 + ct * 16 + lr) * 40 + qa * 8];
#pragma unroll
                for (int mt = 0; mt < 2; mt++)
                    acc[ct][mt] = __builtin_amdgcn_mfma_f32_16x16x32_bf16(ah[mt], bh, acc[ct][mt], 0, 0, 0);
                if (lo_now) {
                    bf16x8 bl = *(const bf16x8*)&BB[cur][1][(w * 32 + ct * 16 + lr) * 40 + qa * 8];
#pragma unroll
                    for (int mt = 0; mt < 2; mt++) {
                        acc[ct][mt] = __builtin_amdgcn_mfma_f32_16x16x32_bf16(ah[mt], bl, acc[ct][mt], 0, 0, 0);
                        acc[ct][mt] = __builtin_amdgcn_mfma_f32_16x16x32_bf16(al[mt], bh, acc[ct][mt], 0, 0, 0);
                    }
                }
            }
            if (w == 0 && lo_now) {
                bf16x8 bho = *(const bf16x8*)&BB[cur][0][(128 + lr) * 40 + qa * 8];
                bf16x8 blo = *(const bf16x8*)&BB[cur][1][(128 + lr) * 40 + qa * 8];
#pragma unroll
                for (int mt = 0; mt < 2; mt++) {
                    acce[mt] = __builtin_amdgcn_mfma_f32_16x16x32_bf16(ah[mt], bho, acce[mt], 0, 0, 0);
                    acce[mt] = __builtin_amdgcn_mfma_f32_16x16x32_bf16(ah[mt], blo, acce[mt], 0, 0, 0);
                    acce[mt] = __builtin_amdgcn_mfma_f32_16x16x32_bf16(al[mt], bho, acce[mt], 0, 0, 0);
                }
            }
            if (ks < 13) {
                int nb = cur ^ 1;
#pragma unroll
                for (int it = 0; it < 3; it++) {
                    int idx = tid + it * 256;
                    if (idx < 576) {
                        int c = idx >> 2, oct = idx & 3;
                        *(uint4*)&BB[nb][0][c * 40 + oct * 8] = bregH[it];
                        if (lo_nxt)
                            *(uint4*)&BB[nb][1][c * 40 + oct * 8] = bregL[it];
                    }
                }
            }
            __syncthreads();
        }

        // ---- exchange: U[col 0..143][row 0..31] ----
#pragma unroll
        for (int ct = 0; ct < 2; ct++)
#pragma unroll
            for (int mt = 0; mt < 2; mt++)
#pragma unroll
                for (int r = 0; r < 4; r++)
                    U[(w * 32 + ct * 16 + lr) * 33 + (mt * 16 + qa * 4 + r)] = acc[ct][mt][r];
        if (w == 0) {
#pragma unroll
            for (int mt = 0; mt < 2; mt++)
#pragma unroll
                for (int r = 0; r < 4; r++)
                    U[(128 + lr) * 33 + (mt * 16 + qa * 4 + r)] = acce[mt][r];
        }
    }
    __syncthreads();

    // ---- LSTM pointwise (t<SEQ) ----
    if (t < SEQ) {
        int b = tid & 31, hq = tid >> 5;
        unsigned short hh[4], hl[4];
#pragma unroll
        for (int q = 0; q < 4; q++) {
            int hlc = hq * 4 + q;
            int gb = hj * 32 + hlc;
            float iv = U[(0 * 32 + hlc) * 33 + b] + b_ih[gb]        + b_hh[gb];
            float fv = U[(1 * 32 + hlc) * 33 + b] + b_ih[256 + gb]  + b_hh[256 + gb];
            float gv = U[(2 * 32 + hlc) * 33 + b] + b_ih[512 + gb]  + b_hh[512 + gb];
            float ov = U[(3 * 32 + hlc) * 33 + b] + b_ih[768 + gb]  + b_hh[768 + gb];
            size_t cidx = (size_t)gb * 1024 + bg0 + b;
            float c_old = cx[cidx];
            float c_new = fmaf(sigmoidf_(fv), c_old, sigmoidf_(iv) * tanhf(gv));
            cx[cidx] = c_new;
            float hv = sigmoidf_(ov) * tanhf(c_new);
            cvt_hl(hv, hh[q], hl[q]);
        }
        size_t ho = (size_t)(bg0 + b) * 256 + hj * 32 + hq * 4;
        *(ushort4*)&hxh_out[ho] = make_ushort4(hh[0], hh[1], hh[2], hh[3]);
        *(ushort4*)&hxl_out[ho] = make_ushort4(hl[0], hl[1], hl[2], hl[3]);
    }

    // ---- out_{t-1} write from ext cols ----
    if (t > 0) {
        for (int idx = tid; idx < 384; idx += 256) {
            int b = idx / 12, c = idx - b * 12;
            int col = hj * 12 + c;
            if (col < 90) {
                float v = (U[(128 + c) * 33 + b] + b_out[col]) * pitch[col & 1];
                d_out[((size_t)(bg0 + b) * SEQ + (t - 1)) * 90 + col] = v;
            }
        }
    }
}

extern "C" void kernel_launch(void* const* d_in, const int* in_sizes, int n_in,
                              void* d_out, int out_size, void* d_ws, size_t ws_size,
                              hipStream_t stream) {
    const float* coords = (const float*)d_in[0];
    const float* pitch  = (const float*)d_in[1];
    const float* W_e1   = (const float*)d_in[2];
    const float* b_e1   = (const float*)d_in[3];
    const float* W_e2   = (const float*)d_in[4];
    const float* b_e2   = (const float*)d_in[5];
    const float* W_ih   = (const float*)d_in[6];
    const float* b_ih   = (const float*)d_in[7];
    const float* W_hh   = (const float*)d_in[8];
    const float* b_hh   = (const float*)d_in[9];
    const float* W_out  = (const float*)d_in[10];
    const float* b_out  = (const float*)d_in[11];
    float* out = (float*)d_out;
    float* ws  = (float*)d_ws;

    // ws layout (float offsets); total 19,347,968 floats ~= 77.4 MB
    float* cxb = ws;                                          // 262144
    unsigned short* hxhA = (unsigned short*)(ws + 262144);    // 131072 f
    unsigned short* hxlA = (unsigned short*)(ws + 393216);    // 131072 f
    unsigned short* hxhB = (unsigned short*)(ws + 524288);    // 131072 f
    unsigned short* hxlB = (unsigned short*)(ws + 655360);    // 131072 f
    float* WoT = ws + 786432;                                 // 23040
    unsigned short* Wt_h = (unsigned short*)(ws + 809472);    // 258048 f
    unsigned short* Wt_l = (unsigned short*)(ws + 1067520);   // 258048 f
    unsigned short* xin_h = (unsigned short*)(ws + 1325568);  // 18022400 f

    // zero cx + hxhA + hxlA (poisoned 0xAA by harness)
    hipMemsetAsync(ws, 0, (size_t)524288 * sizeof(float), stream);

    transpose_wout<<<90, 256, 0, stream>>>(W_out, WoT);
    prep_wt<<<1152, 256, 0, stream>>>(W_ih, W_hh, W_out, Wt_h, Wt_l);
    enc_kernel<<<SEQ * 16, 256, 0, stream>>>(coords, W_e1, b_e1, W_e2, b_e2, xin_h);

    for (int t = 0; t <= SEQ; t++) {
        bool even = !(t & 1);
        step_kernel<<<256, 256, 0, stream>>>(
            t, xin_h,
            even ? hxhA : hxhB, even ? hxlA : hxlB,
            even ? hxhB : hxhA, even ? hxlB : hxlA,
            cxb, Wt_h, Wt_l, b_ih, b_hh, WoT, b_out, pitch, out);
    }
}

// Round 6
// 3165.641 us; speedup vs baseline: 2.1252x; 2.1252x over previous
//
#include <hip/hip_runtime.h>
#include <math.h>

#define SEQ 200

typedef float f32x4 __attribute__((ext_vector_type(4)));
typedef short bf16x8 __attribute__((ext_vector_type(8)));

__device__ __forceinline__ float sigmoidf_(float x) { return 1.0f / (1.0f + __expf(-x)); }

__device__ __forceinline__ unsigned short bf16_rn(float v) {
    unsigned x = __float_as_uint(v);
    unsigned r = x + 0x7FFFu + ((x >> 16) & 1u);
    return (unsigned short)(r >> 16);
}
__device__ __forceinline__ float bf16_to_f(unsigned short h) {
    return __uint_as_float(((unsigned)h) << 16);
}
__device__ __forceinline__ void cvt_hl(float v, unsigned short& h, unsigned short& l) {
    h = bf16_rn(v);
    l = bf16_rn(v - bf16_to_f(h));
}

// ---------------- W_out transpose: WoT[90][256] ----------------
__global__ void transpose_wout(const float* __restrict__ W_out, float* __restrict__ WoT) {
    int c = blockIdx.x;      // 0..89
    int k = threadIdx.x;     // 0..255
    WoT[c * 256 + k] = W_out[k * 90 + c];
}

// ---------------- Wt prep: Wt_h/Wt_l[1024 rc][448 k] bf16 ----------------
// rc = hj*128 + lc; gcol = (lc>>5)*256 + hj*32 + (lc&31). k: 0-174 W_ih, 175 zero,
// 176-431 W_hh, 432-447 zero.
__global__ void prep_wt(const float* __restrict__ W_ih, const float* __restrict__ W_hh,
                        unsigned short* __restrict__ Wt_h, unsigned short* __restrict__ Wt_l) {
    int rc = blockIdx.x;
    int hj = rc >> 7, lc = rc & 127;
    int gcol = (lc >> 5) * 256 + hj * 32 + (lc & 31);
    for (int k = threadIdx.x; k < 448; k += 256) {
        float v = 0.f;
        if (k < 175) v = W_ih[(size_t)k * 1024 + gcol];
        else if (k >= 176 && k < 432) v = W_hh[(size_t)(k - 176) * 1024 + gcol];
        unsigned short h, l; cvt_hl(v, h, l);
        Wt_h[(size_t)rc * 448 + k] = h;
        Wt_l[(size_t)rc * 448 + k] = l;
    }
}

// ---------------- Encoder -> xin_h[t][b][176] bf16 ----------------
__global__ __launch_bounds__(256) void enc_kernel(
    const float* __restrict__ coords,
    const float* __restrict__ W_e1, const float* __restrict__ b_e1,
    const float* __restrict__ W_e2, const float* __restrict__ b_e2,
    unsigned short* __restrict__ xin_h)
{
    __shared__ float C[64][89];
    __shared__ float H[64][2][65];
    __shared__ float W2[64][64];
    __shared__ float O[128][65];   // padded to kill column-write bank conflicts

    int t  = blockIdx.x >> 4;
    int bc = blockIdx.x & 15;
    int tid = threadIdx.x;

    for (int idx = tid; idx < 64 * 88; idx += 256) {
        int bl = idx / 88, j = idx - bl * 88;
        C[bl][j] = coords[((size_t)(bc * 64 + bl) * SEQ + t) * 88 + j];
    }
    for (int idx = tid; idx < 64 * 64; idx += 256)
        W2[idx >> 6][idx & 63] = W_e2[idx];
    __syncthreads();

    {
        int b  = tid >> 2;
        int cq = (tid & 3) * 16;
        float w0[16], w1[16], bb[16];
#pragma unroll
        for (int c = 0; c < 16; c++) { w0[c] = W_e1[cq + c]; w1[c] = W_e1[64 + cq + c]; bb[c] = b_e1[cq + c]; }
        for (int tm = 0; tm < 2; tm++) {
            float acc[16];
#pragma unroll
            for (int c = 0; c < 16; c++) acc[c] = 0.f;
            for (int p = 0; p < 11; p++) {
                float x = C[b][(tm * 11 + p) * 4];
                float y = C[b][(tm * 11 + p) * 4 + 1];
#pragma unroll
                for (int c = 0; c < 16; c++) {
                    float h = fmaf(x, w0[c], fmaf(y, w1[c], bb[c]));
                    acc[c] += fmaxf(h, 0.f);
                }
            }
#pragma unroll
            for (int c = 0; c < 16; c++) H[b][tm][cq + c] = acc[c] * (1.0f / 11.0f);
        }
    }
    __syncthreads();

    {
        int b  = tid >> 2;
        int tm = (tid >> 1) & 1;
        int ch = (tid & 1) * 32;
        float acc[32];
#pragma unroll
        for (int c = 0; c < 32; c++) acc[c] = 0.f;
        for (int k = 0; k < 64; k++) {
            float h = H[b][tm][k];
#pragma unroll
            for (int c = 0; c < 32; c++) acc[c] = fmaf(h, W2[k][ch + c], acc[c]);
        }
#pragma unroll
        for (int c = 0; c < 32; c++) O[tm * 64 + ch + c][b] = acc[c] + b_e2[ch + c];
    }
    __syncthreads();

    unsigned short* xrow = xin_h + ((size_t)t * 1024 + bc * 64) * 176;
    for (int idx = tid; idx < 64 * 22; idx += 256) {
        int bl = idx / 22, oct = idx - bl * 22;
        unsigned short hs[8];
#pragma unroll
        for (int e = 0; e < 8; e++) {
            int k = oct * 8 + e;
            float v;
            if (k < 44)       v = C[bl][(k >> 1) * 4 + (k & 1)];
            else if (k < 172) v = O[k - 44][bl];
            else              v = 0.f;
            hs[e] = bf16_rn(v);
        }
        uint4 pk;
        pk.x = (unsigned)hs[0] | ((unsigned)hs[1] << 16);
        pk.y = (unsigned)hs[2] | ((unsigned)hs[3] << 16);
        pk.z = (unsigned)hs[4] | ((unsigned)hs[5] << 16);
        pk.w = (unsigned)hs[6] | ((unsigned)hs[7] << 16);
        *(uint4*)(xrow + (size_t)bl * 176 + oct * 8) = pk;
    }
}

// ---------------- Per-step kernel (MFMA, wave-specialized) ----------------
// grid 256, 512 threads: waves 0-3 (tid<256) = round-4 compute path verbatim;
// waves 4-7 = B-staging producers in the K-loop. 2 waves/SIMD.
__global__ __launch_bounds__(512, 1) void step_kernel(
    int t,
    const unsigned short* __restrict__ xin_h,
    const unsigned short* __restrict__ hxh_in, const unsigned short* __restrict__ hxl_in,
    unsigned short* __restrict__ hxh_out, unsigned short* __restrict__ hxl_out,
    const float* __restrict__ hx_in, float* __restrict__ hx_out, float* __restrict__ cx,
    const unsigned short* __restrict__ Wt_h, const unsigned short* __restrict__ Wt_l,
    const float* __restrict__ b_ih, const float* __restrict__ b_hh,
    const float* __restrict__ WoT, const float* __restrict__ b_out,
    const float* __restrict__ pitch, float* __restrict__ d_out)
{
    __shared__ unsigned short AH[32 * 456];        // 29184 B
    __shared__ unsigned short AL[32 * 456];        // 29184 B
    __shared__ unsigned short BB[2][2][128 * 40];  // 40960 B
    __shared__ float U[128 * 33];                  // 16896 B  P scratch / G gates
    __shared__ float Wo[14 * 256];                 // 14336 B
    __shared__ float predL[32][2];                 // 256 B

    int tid = threadIdx.x;
    int bi = blockIdx.x & 31, hj = blockIdx.x >> 5;
    int bg0 = bi * 32;

    // ---- stage (all 512 threads) ----
    if (t < SEQ) {
        const unsigned short* xr = xin_h + ((size_t)t * 1024 + bg0) * 176;
        for (int idx = tid; idx < 32 * 22; idx += 512) {
            int b = idx / 22, oct = idx - b * 22;
            *(uint4*)&AH[b * 456 + oct * 8] = *(const uint4*)(xr + (size_t)b * 176 + oct * 8);
            *(uint4*)&AL[b * 456 + oct * 8] = make_uint4(0, 0, 0, 0);
        }
        for (int idx = tid; idx < 32 * 32; idx += 512) {
            int b = idx >> 5, oct = idx & 31;
            *(uint4*)&AH[b * 456 + 176 + oct * 8] =
                *(const uint4*)(hxh_in + (size_t)(bg0 + b) * 256 + oct * 8);
            *(uint4*)&AL[b * 456 + 176 + oct * 8] =
                *(const uint4*)(hxl_in + (size_t)(bg0 + b) * 256 + oct * 8);
        }
        if (tid < 64) {
            int b = tid >> 1, oct = tid & 1;
            *(uint4*)&AH[b * 456 + 432 + oct * 8] = make_uint4(0, 0, 0, 0);
            *(uint4*)&AL[b * 456 + 432 + oct * 8] = make_uint4(0, 0, 0, 0);
        }
        // B chunk ks=0 (h + l), 512 items, one per thread
        {
            const unsigned short* wbh = Wt_h + (size_t)(hj * 128) * 448;
            const unsigned short* wbl = Wt_l + (size_t)(hj * 128) * 448;
            int c = tid >> 2, oct = tid & 3;
            *(uint4*)&BB[0][0][c * 40 + oct * 8] = *(const uint4*)(wbh + (size_t)c * 448 + oct * 8);
            *(uint4*)&BB[0][1][c * 40 + oct * 8] = *(const uint4*)(wbl + (size_t)c * 448 + oct * 8);
        }
    }
    for (int idx = tid; idx < 14 * 256; idx += 512) {
        int c = idx >> 8, k = idx & 255;
        int col = (c < 12) ? (hj * 12 + c) : (88 + (c - 12));
        Wo[idx] = (col < 90) ? WoT[col * 256 + k] : 0.f;
    }
    __syncthreads();

    // ---- out_{t-1} + pred_{t-1} = hx_{t-1}(fp32) @ Wo  (tid<256) ----
    if (tid < 256) {
        int b = tid & 31, kq = tid >> 5;     // kq 0..7
        float accO[14];
#pragma unroll
        for (int c = 0; c < 14; c++) accO[c] = 0.f;
        if (t > 0) {
#pragma unroll 4
            for (int k = 0; k < 32; k++) {
                float xv = hx_in[(size_t)(kq * 32 + k) * 1024 + bg0 + b];
#pragma unroll
                for (int c = 0; c < 14; c++) accO[c] = fmaf(xv, Wo[c * 256 + kq * 32 + k], accO[c]);
            }
        }
        float* P = U;   // [8][32][14]
#pragma unroll
        for (int c = 0; c < 14; c++) P[(kq * 32 + b) * 14 + c] = accO[c];
    }
    __syncthreads();
    if (tid < 256) {
        for (int idx = tid; idx < 448; idx += 256) {
            int b = idx / 14, c = idx - b * 14;
            float s = 0.f;
#pragma unroll
            for (int kq = 0; kq < 8; kq++) s += U[(kq * 32 + b) * 14 + c];
            int col = (c < 12) ? (hj * 12 + c) : (76 + c);
            if (col < 90) {
                if (t > 0) {
                    float v = (s + b_out[col]) * pitch[col & 1];
                    if (c < 12) d_out[((size_t)(bg0 + b) * SEQ + (t - 1)) * 90 + col] = v;
                    else predL[b][c - 12] = v;
                } else if (c >= 12) {
                    predL[b][c - 12] = 0.f;
                }
            }
        }
    }
    __syncthreads();

    if (t < SEQ) {
        // ---- closest distance; fill A rows 172..174 ----
        if (tid < 32) {
            int b = tid;
            float p0 = predL[b][0], p1 = predL[b][1];
            float m = 1e30f;
#pragma unroll
            for (int p = 0; p < 22; p++) {
                float px = bf16_to_f(AH[b * 456 + 2 * p]);
                float py = bf16_to_f(AH[b * 456 + 2 * p + 1]);
                float dx = p0 - px, dy = p1 - py;
                m = fminf(m, fmaf(dx, dx, dy * dy));
            }
            unsigned short h, l;
            cvt_hl(sqrtf(m), h, l); AH[b * 456 + 172] = h; AL[b * 456 + 172] = l;
            cvt_hl(p0, h, l);       AH[b * 456 + 173] = h; AL[b * 456 + 173] = l;
            cvt_hl(p1, h, l);       AH[b * 456 + 174] = h; AL[b * 456 + 174] = l;
        }
        __syncthreads();

        // ---- K-loop: 14 x K=32; consumers (tid<256) compute, producers stage ----
        if (tid < 256) {
            int l = tid & 63, w = tid >> 6;      // w 0..3
            int lr = l & 15, qa = l >> 4;

            f32x4 acc[2][2];
#pragma unroll
            for (int ct = 0; ct < 2; ct++)
#pragma unroll
                for (int mt = 0; mt < 2; mt++) acc[ct][mt] = (f32x4){0.f, 0.f, 0.f, 0.f};

            for (int ks = 0; ks < 14; ks++) {
                int cur = ks & 1;
                bf16x8 ah[2], al[2], bh[2], bl[2];
#pragma unroll
                for (int mt = 0; mt < 2; mt++) {
                    ah[mt] = *(const bf16x8*)&AH[(mt * 16 + lr) * 456 + ks * 32 + qa * 8];
                    al[mt] = *(const bf16x8*)&AL[(mt * 16 + lr) * 456 + ks * 32 + qa * 8];
                }
#pragma unroll
                for (int ct = 0; ct < 2; ct++) {
                    bh[ct] = *(const bf16x8*)&BB[cur][0][(w * 32 + ct * 16 + lr) * 40 + qa * 8];
                    bl[ct] = *(const bf16x8*)&BB[cur][1][(w * 32 + ct * 16 + lr) * 40 + qa * 8];
                }
#pragma unroll
                for (int ct = 0; ct < 2; ct++)
#pragma unroll
                    for (int mt = 0; mt < 2; mt++) {
                        acc[ct][mt] = __builtin_amdgcn_mfma_f32_16x16x32_bf16(ah[mt], bh[ct], acc[ct][mt], 0, 0, 0);
                        acc[ct][mt] = __builtin_amdgcn_mfma_f32_16x16x32_bf16(ah[mt], bl[ct], acc[ct][mt], 0, 0, 0);
                        acc[ct][mt] = __builtin_amdgcn_mfma_f32_16x16x32_bf16(al[mt], bh[ct], acc[ct][mt], 0, 0, 0);
                    }
                __syncthreads();
            }

            // ---- G exchange: U[col][33] ----
#pragma unroll
            for (int ct = 0; ct < 2; ct++)
#pragma unroll
                for (int mt = 0; mt < 2; mt++)
#pragma unroll
                    for (int r = 0; r < 4; r++)
                        U[(w * 32 + ct * 16 + lr) * 33 + (mt * 16 + qa * 4 + r)] = acc[ct][mt][r];
        } else {
            // producers: stage chunk ks+1 into BB[nb]
            int st = tid & 255;
            const unsigned short* wbh = Wt_h + (size_t)(hj * 128) * 448;
            const unsigned short* wbl = Wt_l + (size_t)(hj * 128) * 448;
            for (int ks = 0; ks < 14; ks++) {
                if (ks < 13) {
                    int ko = (ks + 1) * 32;
                    int nb = (ks & 1) ^ 1;
                    uint4 hA, lA, hB, lB;
                    {
                        int c = st >> 2, oct = st & 3;
                        hA = *(const uint4*)(wbh + (size_t)c * 448 + ko + oct * 8);
                        lA = *(const uint4*)(wbl + (size_t)c * 448 + ko + oct * 8);
                    }
                    {
                        int idx = st + 256;
                        int c = idx >> 2, oct = idx & 3;
                        hB = *(const uint4*)(wbh + (size_t)c * 448 + ko + oct * 8);
                        lB = *(const uint4*)(wbl + (size_t)c * 448 + ko + oct * 8);
                    }
                    {
                        int c = st >> 2, oct = st & 3;
                        *(uint4*)&BB[nb][0][c * 40 + oct * 8] = hA;
                        *(uint4*)&BB[nb][1][c * 40 + oct * 8] = lA;
                    }
                    {
                        int idx = st + 256;
                        int c = idx >> 2, oct = idx & 3;
                        *(uint4*)&BB[nb][0][c * 40 + oct * 8] = hB;
                        *(uint4*)&BB[nb][1][c * 40 + oct * 8] = lB;
                    }
                }
                __syncthreads();
            }
        }
        __syncthreads();

        // ---- LSTM pointwise (tid<256) ----
        if (tid < 256) {
            int b = tid & 31, hq = tid >> 5;   // hq 0..7
            unsigned short hh[4], hl[4];
#pragma unroll
            for (int q = 0; q < 4; q++) {
                int hlc = hq * 4 + q;          // 0..31
                int gb = hj * 32 + hlc;
                float iv = U[(0 * 32 + hlc) * 33 + b] + b_ih[gb]        + b_hh[gb];
                float fv = U[(1 * 32 + hlc) * 33 + b] + b_ih[256 + gb]  + b_hh[256 + gb];
                float gv = U[(2 * 32 + hlc) * 33 + b] + b_ih[512 + gb]  + b_hh[512 + gb];
                float ov = U[(3 * 32 + hlc) * 33 + b] + b_ih[768 + gb]  + b_hh[768 + gb];
                size_t cidx = (size_t)gb * 1024 + bg0 + b;
                float c_old = cx[cidx];
                float c_new = fmaf(sigmoidf_(fv), c_old, sigmoidf_(iv) * tanhf(gv));
                cx[cidx] = c_new;
                float hv = sigmoidf_(ov) * tanhf(c_new);
                hx_out[cidx] = hv;
                cvt_hl(hv, hh[q], hl[q]);
            }
            size_t ho = (size_t)(bg0 + b) * 256 + hj * 32 + hq * 4;
            *(ushort4*)&hxh_out[ho] = make_ushort4(hh[0], hh[1], hh[2], hh[3]);
            *(ushort4*)&hxl_out[ho] = make_ushort4(hl[0], hl[1], hl[2], hl[3]);
        }
    }
}

extern "C" void kernel_launch(void* const* d_in, const int* in_sizes, int n_in,
                              void* d_out, int out_size, void* d_ws, size_t ws_size,
                              hipStream_t stream) {
    const float* coords = (const float*)d_in[0];
    const float* pitch  = (const float*)d_in[1];
    const float* W_e1   = (const float*)d_in[2];
    const float* b_e1   = (const float*)d_in[3];
    const float* W_e2   = (const float*)d_in[4];
    const float* b_e2   = (const float*)d_in[5];
    const float* W_ih   = (const float*)d_in[6];
    const float* b_ih   = (const float*)d_in[7];
    const float* W_hh   = (const float*)d_in[8];
    const float* b_hh   = (const float*)d_in[9];
    const float* W_out  = (const float*)d_in[10];
    const float* b_out  = (const float*)d_in[11];
    float* out = (float*)d_out;
    float* ws  = (float*)d_ws;

    // ws layout (float offsets)
    float* hxA   = ws;                                            // 262144
    float* cxb   = ws + 262144;                                   // 262144
    unsigned short* hxhA = (unsigned short*)(ws + 524288);        // 131072 f
    unsigned short* hxlA = (unsigned short*)(ws + 655360);        // 131072 f
    float* hxB   = ws + 786432;                                   // 262144
    unsigned short* hxhB = (unsigned short*)(ws + 1048576);       // 131072 f
    unsigned short* hxlB = (unsigned short*)(ws + 1179648);       // 131072 f
    float* WoT   = ws + 1310720;                                  // 23040
    unsigned short* Wt_h = (unsigned short*)(ws + 1333760);       // 229376 f
    unsigned short* Wt_l = (unsigned short*)(ws + 1563136);       // 229376 f
    unsigned short* xin_h = (unsigned short*)(ws + 1792512);      // 18022400 f

    // zero hxA + cx + hxhA + hxlA (poisoned 0xAA by harness)
    hipMemsetAsync(ws, 0, (size_t)786432 * sizeof(float), stream);

    transpose_wout<<<90, 256, 0, stream>>>(W_out, WoT);
    prep_wt<<<1024, 256, 0, stream>>>(W_ih, W_hh, Wt_h, Wt_l);
    enc_kernel<<<SEQ * 16, 256, 0, stream>>>(coords, W_e1, b_e1, W_e2, b_e2, xin_h);

    for (int t = 0; t <= SEQ; t++) {
        bool even = !(t & 1);
        step_kernel<<<256, 512, 0, stream>>>(
            t, xin_h,
            even ? hxhA : hxhB, even ? hxlA : hxlB,
            even ? hxhB : hxhA, even ? hxlB : hxlA,
            even ? hxA : hxB, even ? hxB : hxA, cxb,
            Wt_h, Wt_l, b_ih, b_hh, WoT, b_out, pitch, out);
    }
}

// Round 7
// 2448.304 us; speedup vs baseline: 2.7478x; 1.2930x over previous
//
#include <hip/hip_runtime.h>
#include <math.h>

#define SEQ 200

typedef float f32x4 __attribute__((ext_vector_type(4)));
typedef short bf16x8 __attribute__((ext_vector_type(8)));

__device__ __forceinline__ float sigmoidf_(float x) { return 1.0f / (1.0f + __expf(-x)); }

__device__ __forceinline__ unsigned short bf16_rn(float v) {
    unsigned x = __float_as_uint(v);
    unsigned r = x + 0x7FFFu + ((x >> 16) & 1u);
    return (unsigned short)(r >> 16);
}
__device__ __forceinline__ float bf16_to_f(unsigned short h) {
    return __uint_as_float(((unsigned)h) << 16);
}
__device__ __forceinline__ void cvt_hl(float v, unsigned short& h, unsigned short& l) {
    h = bf16_rn(v);
    l = bf16_rn(v - bf16_to_f(h));
}

// ---------------- Wt prep: Wt_h/Wt_l[1024 rc][448 k] bf16 ----------------
__global__ void prep_wt(const float* __restrict__ W_ih, const float* __restrict__ W_hh,
                        unsigned short* __restrict__ Wt_h, unsigned short* __restrict__ Wt_l) {
    int rc = blockIdx.x;
    int hj = rc >> 7, lc = rc & 127;
    int gcol = (lc >> 5) * 256 + hj * 32 + (lc & 31);
    for (int k = threadIdx.x; k < 448; k += 256) {
        float v = 0.f;
        if (k < 175) v = W_ih[(size_t)k * 1024 + gcol];
        else if (k >= 176 && k < 432) v = W_hh[(size_t)(k - 176) * 1024 + gcol];
        unsigned short h, l; cvt_hl(v, h, l);
        Wt_h[(size_t)rc * 448 + k] = h;
        Wt_l[(size_t)rc * 448 + k] = l;
    }
}

// ---------------- Wt_o prep: [128 rc = hj*16+c][256 k] bf16 h/l ----------------
// c<12: out col hj*12+c (0 if >=90); c=12,13: pred cols 88,89; c=14,15: zero.
__global__ void prep_wo(const float* __restrict__ W_out,
                        unsigned short* __restrict__ Wt_oh, unsigned short* __restrict__ Wt_ol) {
    int rc = blockIdx.x;
    int hj = rc >> 4, c = rc & 15;
    int col = (c < 12) ? (hj * 12 + c) : (c < 14 ? 76 + c : 999);
    for (int k = threadIdx.x; k < 256; k += 256) {
        float v = (col < 90) ? W_out[(size_t)k * 90 + col] : 0.f;
        unsigned short h, l; cvt_hl(v, h, l);
        Wt_oh[(size_t)rc * 256 + k] = h;
        Wt_ol[(size_t)rc * 256 + k] = l;
    }
}

// ---------------- Encoder -> xin_h[t][b][176] bf16 (32-batch blocks) ----------
__global__ __launch_bounds__(256, 2) void enc_kernel(
    const float* __restrict__ coords,
    const float* __restrict__ W_e1, const float* __restrict__ b_e1,
    const float* __restrict__ W_e2, const float* __restrict__ b_e2,
    unsigned short* __restrict__ xin_h)
{
    __shared__ float C[32][89];
    __shared__ float H[32][2][65];
    __shared__ float W2[64][64];
    __shared__ float O[128][33];

    int t  = blockIdx.x >> 5;
    int bc = blockIdx.x & 31;
    int tid = threadIdx.x;

    for (int idx = tid; idx < 32 * 88; idx += 256) {
        int bl = idx / 88, j = idx - bl * 88;
        C[bl][j] = coords[((size_t)(bc * 32 + bl) * SEQ + t) * 88 + j];
    }
    for (int idx = tid; idx < 64 * 64; idx += 256)
        W2[idx >> 6][idx & 63] = W_e2[idx];
    __syncthreads();

    {   // phase A: 8 threads/row, 8 cols each
        int b  = tid >> 3;
        int cq = (tid & 7) * 8;
        float w0[8], w1[8], bb[8];
#pragma unroll
        for (int c = 0; c < 8; c++) { w0[c] = W_e1[cq + c]; w1[c] = W_e1[64 + cq + c]; bb[c] = b_e1[cq + c]; }
        for (int tm = 0; tm < 2; tm++) {
            float acc[8];
#pragma unroll
            for (int c = 0; c < 8; c++) acc[c] = 0.f;
            for (int p = 0; p < 11; p++) {
                float x = C[b][(tm * 11 + p) * 4];
                float y = C[b][(tm * 11 + p) * 4 + 1];
#pragma unroll
                for (int c = 0; c < 8; c++) {
                    float h = fmaf(x, w0[c], fmaf(y, w1[c], bb[c]));
                    acc[c] += fmaxf(h, 0.f);
                }
            }
#pragma unroll
            for (int c = 0; c < 8; c++) H[b][tm][cq + c] = acc[c] * (1.0f / 11.0f);
        }
    }
    __syncthreads();

    {   // phase B: 8 threads/row: tm split, 16 cols each
        int b  = tid >> 3;
        int tm = (tid >> 2) & 1;
        int ch = (tid & 3) * 16;
        float acc[16];
#pragma unroll
        for (int c = 0; c < 16; c++) acc[c] = 0.f;
        for (int k = 0; k < 64; k++) {
            float h = H[b][tm][k];
#pragma unroll
            for (int c = 0; c < 16; c++) acc[c] = fmaf(h, W2[k][ch + c], acc[c]);
        }
#pragma unroll
        for (int c = 0; c < 16; c++) O[tm * 64 + ch + c][b] = acc[c] + b_e2[ch + c];
    }
    __syncthreads();

    unsigned short* xrow = xin_h + ((size_t)t * 1024 + bc * 32) * 176;
    for (int idx = tid; idx < 32 * 22; idx += 256) {
        int bl = idx / 22, oct = idx - bl * 22;
        unsigned short hs[8];
#pragma unroll
        for (int e = 0; e < 8; e++) {
            int k = oct * 8 + e;
            float v;
            if (k < 44)       v = C[bl][(k >> 1) * 4 + (k & 1)];
            else if (k < 172) v = O[k - 44][bl];
            else              v = 0.f;
            hs[e] = bf16_rn(v);
        }
        uint4 pk;
        pk.x = (unsigned)hs[0] | ((unsigned)hs[1] << 16);
        pk.y = (unsigned)hs[2] | ((unsigned)hs[3] << 16);
        pk.z = (unsigned)hs[4] | ((unsigned)hs[5] << 16);
        pk.w = (unsigned)hs[6] | ((unsigned)hs[7] << 16);
        *(uint4*)(xrow + (size_t)bl * 176 + oct * 8) = pk;
    }
}

#define MFMA_B(d, a, b) d = __builtin_amdgcn_mfma_f32_16x16x32_bf16(a, b, d, 0, 0, 0)

#define P_LOAD(R0, R1, R2, R3, KO) \
    R0 = *(const uint4*)(wbh + (size_t)c0 * 448 + (KO) + oct * 8); \
    R1 = *(const uint4*)(wbl + (size_t)c0 * 448 + (KO) + oct * 8); \
    R2 = *(const uint4*)(wbh + (size_t)c1 * 448 + (KO) + oct * 8); \
    R3 = *(const uint4*)(wbl + (size_t)c1 * 448 + (KO) + oct * 8);

#define P_STORE(R0, R1, R2, R3, NB) \
    *(uint4*)&BB[NB][0][c0 * 40 + oct * 8] = R0; \
    *(uint4*)&BB[NB][1][c0 * 40 + oct * 8] = R1; \
    *(uint4*)&BB[NB][0][c1 * 40 + oct * 8] = R2; \
    *(uint4*)&BB[NB][1][c1 * 40 + oct * 8] = R3;

// ---------------- Per-step kernel ----------------
// grid 256 x 512 threads: waves 0-3 compute (out-MFMA + gates K-loop),
// waves 4-7 stage B chunks, 3-buffer rotation, loads issued 2 segments early.
__global__ __launch_bounds__(512, 1) void step_kernel(
    int t,
    const unsigned short* __restrict__ xin_h,
    const unsigned short* __restrict__ hxh_in, const unsigned short* __restrict__ hxl_in,
    unsigned short* __restrict__ hxh_out, unsigned short* __restrict__ hxl_out,
    float* __restrict__ cx,
    const unsigned short* __restrict__ Wt_h, const unsigned short* __restrict__ Wt_l,
    const unsigned short* __restrict__ Wt_oh, const unsigned short* __restrict__ Wt_ol,
    const float* __restrict__ b_ih, const float* __restrict__ b_hh,
    const float* __restrict__ b_out,
    const float* __restrict__ pitch, float* __restrict__ d_out)
{
    __shared__ unsigned short AH[32 * 456];        // 29184 B
    __shared__ unsigned short AL[32 * 456];        // 29184 B
    __shared__ unsigned short BB[3][2][128 * 40];  // 61440 B
    __shared__ float U[128 * 33];                  // 16896 B: out partials / G gates
    __shared__ float predL[32][2];                 // 256 B

    int tid = threadIdx.x;
    int bi = blockIdx.x & 31, hj = blockIdx.x >> 5;
    int bg0 = bi * 32;
    int l = tid & 63, w = (tid >> 6) & 3;
    int lr = l & 15, qa = l >> 4;

    const unsigned short* wbh = Wt_h + (size_t)(hj * 128) * 448;
    const unsigned short* wbl = Wt_l + (size_t)(hj * 128) * 448;

    // ---- stage ----
    for (int idx = tid; idx < 32 * 32; idx += 512) {   // hx rows 176..431 (always)
        int b = idx >> 5, oct = idx & 31;
        *(uint4*)&AH[b * 456 + 176 + oct * 8] =
            *(const uint4*)(hxh_in + (size_t)(bg0 + b) * 256 + oct * 8);
        *(uint4*)&AL[b * 456 + 176 + oct * 8] =
            *(const uint4*)(hxl_in + (size_t)(bg0 + b) * 256 + oct * 8);
    }
    if (t < SEQ) {
        const unsigned short* xr = xin_h + ((size_t)t * 1024 + bg0) * 176;
        for (int idx = tid; idx < 32 * 22; idx += 512) {     // x rows 0..175
            int b = idx / 22, oct = idx - b * 22;
            *(uint4*)&AH[b * 456 + oct * 8] = *(const uint4*)(xr + (size_t)b * 176 + oct * 8);
        }
        if (tid < 64) {   // AL k160..175 zero; AH/AL tails k432..447 zero
            int b = tid >> 1, h8 = (tid & 1) * 8;
            *(uint4*)&AL[b * 456 + 160 + h8] = make_uint4(0, 0, 0, 0);
            *(uint4*)&AH[b * 456 + 432 + h8] = make_uint4(0, 0, 0, 0);
            *(uint4*)&AL[b * 456 + 432 + h8] = make_uint4(0, 0, 0, 0);
        }
        {   // BB chunk 0
            int c = tid >> 2, oct = tid & 3;
            *(uint4*)&BB[0][0][c * 40 + oct * 8] = *(const uint4*)(wbh + (size_t)c * 448 + oct * 8);
            *(uint4*)&BB[0][1][c * 40 + oct * 8] = *(const uint4*)(wbl + (size_t)c * 448 + oct * 8);
        }
    }
    __syncthreads();   // B1

    // ---- out-MFMA (waves 0-3) / producer prologue loads (waves 4-7) ----
    uint4 rA0, rA1, rA2, rA3, rB0, rB1, rB2, rB3;
    int c0 = (tid & 255) >> 2, oct = tid & 3, c1 = ((tid & 255) >> 2) + 64;
    if (tid < 256) {
        const unsigned short* woh = Wt_oh + ((size_t)(hj * 16 + lr)) * 256 + w * 64 + qa * 8;
        const unsigned short* wol = Wt_ol + ((size_t)(hj * 16 + lr)) * 256 + w * 64 + qa * 8;
        bf16x8 bh0 = *(const bf16x8*)(woh);
        bf16x8 bl0 = *(const bf16x8*)(wol);
        bf16x8 bh1 = *(const bf16x8*)(woh + 32);
        bf16x8 bl1 = *(const bf16x8*)(wol + 32);
        f32x4 acce[2];
        acce[0] = (f32x4){0.f, 0.f, 0.f, 0.f};
        acce[1] = (f32x4){0.f, 0.f, 0.f, 0.f};
#pragma unroll
        for (int ks2 = 0; ks2 < 2; ks2++) {
            bf16x8 bh = ks2 ? bh1 : bh0;
            bf16x8 bl = ks2 ? bl1 : bl0;
#pragma unroll
            for (int mt = 0; mt < 2; mt++) {
                bf16x8 ah = *(const bf16x8*)&AH[(mt * 16 + lr) * 456 + 176 + w * 64 + ks2 * 32 + qa * 8];
                bf16x8 al = *(const bf16x8*)&AL[(mt * 16 + lr) * 456 + 176 + w * 64 + ks2 * 32 + qa * 8];
                MFMA_B(acce[mt], ah, bh);
                MFMA_B(acce[mt], ah, bl);
                MFMA_B(acce[mt], al, bh);
            }
        }
#pragma unroll
        for (int mt = 0; mt < 2; mt++)
#pragma unroll
            for (int r = 0; r < 4; r++)
                U[w * 512 + (mt * 16 + qa * 4 + r) * 16 + lr] = acce[mt][r];
    } else if (t < SEQ) {
        P_LOAD(rA0, rA1, rA2, rA3, 32)    // chunk 1
        P_LOAD(rB0, rB1, rB2, rB3, 64)    // chunk 2
    }
    __syncthreads();   // B2

    // ---- reduce partials; write out_{t-1}; pred -> predL ----
    if (tid < 256) {
#pragma unroll
        for (int j = 0; j < 2; j++) {
            int i = tid * 2 + j;
            int b = i >> 4, c = i & 15;
            float v = U[i] + U[512 + i] + U[1024 + i] + U[1536 + i];
            if (c < 14) {
                int col = (c < 12) ? (hj * 12 + c) : (76 + c);
                if (col < 90) {
                    if (t > 0) {
                        float vv = (v + b_out[col]) * pitch[c & 1];
                        if (c < 12) d_out[((size_t)(bg0 + b) * SEQ + (t - 1)) * 90 + col] = vv;
                        else predL[b][c - 12] = vv;
                    } else if (c >= 12) {
                        predL[b][c - 12] = 0.f;
                    }
                }
            }
        }
    }
    __syncthreads();   // B3

    if (t < SEQ) {
        // ---- closest distance; fill A rows 172..174 ----
        if (tid < 32) {
            int b = tid;
            float p0 = predL[b][0], p1 = predL[b][1];
            float m = 1e30f;
#pragma unroll
            for (int p = 0; p < 22; p++) {
                float px = bf16_to_f(AH[b * 456 + 2 * p]);
                float py = bf16_to_f(AH[b * 456 + 2 * p + 1]);
                float dx = p0 - px, dy = p1 - py;
                m = fminf(m, fmaf(dx, dx, dy * dy));
            }
            unsigned short h, lo;
            cvt_hl(sqrtf(m), h, lo); AH[b * 456 + 172] = h; AL[b * 456 + 172] = lo;
            cvt_hl(p0, h, lo);       AH[b * 456 + 173] = h; AL[b * 456 + 173] = lo;
            cvt_hl(p1, h, lo);       AH[b * 456 + 174] = h; AL[b * 456 + 174] = lo;
        }
        __syncthreads();   // B4

        if (tid < 256) {
            // ---- consumer K-loop: 14 x K=32, fully unrolled, 3-buf ----
            f32x4 acc[2][2];
#pragma unroll
            for (int ct = 0; ct < 2; ct++)
#pragma unroll
                for (int mt = 0; mt < 2; mt++) acc[ct][mt] = (f32x4){0.f, 0.f, 0.f, 0.f};

#pragma unroll
            for (int ks = 0; ks < 14; ks++) {
                const int cur = ks % 3;
                bf16x8 ah[2], al[2], bh[2], bl[2];
#pragma unroll
                for (int mt = 0; mt < 2; mt++)
                    ah[mt] = *(const bf16x8*)&AH[(mt * 16 + lr) * 456 + ks * 32 + qa * 8];
                if (ks >= 5) {
#pragma unroll
                    for (int mt = 0; mt < 2; mt++)
                        al[mt] = *(const bf16x8*)&AL[(mt * 16 + lr) * 456 + ks * 32 + qa * 8];
                }
#pragma unroll
                for (int ct = 0; ct < 2; ct++) {
                    bh[ct] = *(const bf16x8*)&BB[cur][0][(w * 32 + ct * 16 + lr) * 40 + qa * 8];
                    bl[ct] = *(const bf16x8*)&BB[cur][1][(w * 32 + ct * 16 + lr) * 40 + qa * 8];
                }
#pragma unroll
                for (int ct = 0; ct < 2; ct++)
#pragma unroll
                    for (int mt = 0; mt < 2; mt++) {
                        MFMA_B(acc[ct][mt], ah[mt], bh[ct]);
                        MFMA_B(acc[ct][mt], ah[mt], bl[ct]);
                        if (ks >= 5) MFMA_B(acc[ct][mt], al[mt], bh[ct]);
                    }
                __syncthreads();
            }

            // ---- G exchange ----
#pragma unroll
            for (int ct = 0; ct < 2; ct++)
#pragma unroll
                for (int mt = 0; mt < 2; mt++)
#pragma unroll
                    for (int r = 0; r < 4; r++)
                        U[(w * 32 + ct * 16 + lr) * 33 + (mt * 16 + qa * 4 + r)] = acc[ct][mt][r];
        } else {
            // ---- producer loop: store chunk ks+1 (loaded 2 iters ago), issue ks+3 ----
#pragma unroll
            for (int ks = 0; ks < 14; ks++) {
                if (ks <= 12) {
                    const int nb = (ks + 1) % 3;
                    if ((ks & 1) == 0) { P_STORE(rA0, rA1, rA2, rA3, nb) }
                    else               { P_STORE(rB0, rB1, rB2, rB3, nb) }
                }
                if (ks <= 10) {
                    const int ko = (ks + 3) * 32;
                    if ((ks & 1) == 0) { P_LOAD(rA0, rA1, rA2, rA3, ko) }
                    else               { P_LOAD(rB0, rB1, rB2, rB3, ko) }
                }
                __syncthreads();
            }
        }
        __syncthreads();   // B5

        // ---- LSTM pointwise ----
        if (tid < 256) {
            int b = tid & 31, hq = tid >> 5;
            unsigned short hh[4], hl[4];
#pragma unroll
            for (int q = 0; q < 4; q++) {
                int hlc = hq * 4 + q;
                int gb = hj * 32 + hlc;
                float iv = U[(0 * 32 + hlc) * 33 + b] + b_ih[gb]        + b_hh[gb];
                float fv = U[(1 * 32 + hlc) * 33 + b] + b_ih[256 + gb]  + b_hh[256 + gb];
                float gv = U[(2 * 32 + hlc) * 33 + b] + b_ih[512 + gb]  + b_hh[512 + gb];
                float ov = U[(3 * 32 + hlc) * 33 + b] + b_ih[768 + gb]  + b_hh[768 + gb];
                size_t cidx = (size_t)gb * 1024 + bg0 + b;
                float c_old = cx[cidx];
                float c_new = fmaf(sigmoidf_(fv), c_old, sigmoidf_(iv) * tanhf(gv));
                cx[cidx] = c_new;
                float hv = sigmoidf_(ov) * tanhf(c_new);
                cvt_hl(hv, hh[q], hl[q]);
            }
            size_t ho = (size_t)(bg0 + b) * 256 + hj * 32 + hq * 4;
            *(ushort4*)&hxh_out[ho] = make_ushort4(hh[0], hh[1], hh[2], hh[3]);
            *(ushort4*)&hxl_out[ho] = make_ushort4(hl[0], hl[1], hl[2], hl[3]);
        }
    }
}

extern "C" void kernel_launch(void* const* d_in, const int* in_sizes, int n_in,
                              void* d_out, int out_size, void* d_ws, size_t ws_size,
                              hipStream_t stream) {
    const float* coords = (const float*)d_in[0];
    const float* pitch  = (const float*)d_in[1];
    const float* W_e1   = (const float*)d_in[2];
    const float* b_e1   = (const float*)d_in[3];
    const float* W_e2   = (const float*)d_in[4];
    const float* b_e2   = (const float*)d_in[5];
    const float* W_ih   = (const float*)d_in[6];
    const float* b_ih   = (const float*)d_in[7];
    const float* W_hh   = (const float*)d_in[8];
    const float* b_hh   = (const float*)d_in[9];
    const float* W_out  = (const float*)d_in[10];
    const float* b_out  = (const float*)d_in[11];
    float* out = (float*)d_out;
    float* ws  = (float*)d_ws;

    // ws layout (float offsets); total ~19.3M floats ~= 77 MB
    float* cxb = ws;                                          // 262144
    unsigned short* hxhA = (unsigned short*)(ws + 262144);    // 131072 f
    unsigned short* hxlA = (unsigned short*)(ws + 393216);    // 131072 f
    unsigned short* hxhB = (unsigned short*)(ws + 524288);    // 131072 f
    unsigned short* hxlB = (unsigned short*)(ws + 655360);    // 131072 f
    unsigned short* Wt_h = (unsigned short*)(ws + 786432);    // 229376 f
    unsigned short* Wt_l = (unsigned short*)(ws + 1015808);   // 229376 f
    unsigned short* Wt_oh = (unsigned short*)(ws + 1245184);  // 16384 f
    unsigned short* Wt_ol = (unsigned short*)(ws + 1261568);  // 16384 f
    unsigned short* xin_h = (unsigned short*)(ws + 1277952);  // 18022400 f

    // zero cx + hxhA + hxlA (poisoned 0xAA by harness)
    hipMemsetAsync(ws, 0, (size_t)524288 * sizeof(float), stream);

    prep_wt<<<1024, 256, 0, stream>>>(W_ih, W_hh, Wt_h, Wt_l);
    prep_wo<<<128, 256, 0, stream>>>(W_out, Wt_oh, Wt_ol);
    enc_kernel<<<SEQ * 32, 256, 0, stream>>>(coords, W_e1, b_e1, W_e2, b_e2, xin_h);

    for (int t = 0; t <= SEQ; t++) {
        bool even = !(t & 1);
        step_kernel<<<256, 512, 0, stream>>>(
            t, xin_h,
            even ? hxhA : hxhB, even ? hxlA : hxlB,
            even ? hxhB : hxhA, even ? hxlB : hxlA,
            cxb, Wt_h, Wt_l, Wt_oh, Wt_ol, b_ih, b_hh, b_out, pitch, out);
    }
}

// Round 10
// 2379.847 us; speedup vs baseline: 2.8269x; 1.0288x over previous
//
#include <hip/hip_runtime.h>
#include <math.h>

#define SEQ 200

typedef float f32x4 __attribute__((ext_vector_type(4)));
typedef short bf16x8 __attribute__((ext_vector_type(8)));

__device__ __forceinline__ float sigmoidf_(float x) { return 1.0f / (1.0f + __expf(-x)); }

__device__ __forceinline__ unsigned short bf16_rn(float v) {
    unsigned x = __float_as_uint(v);
    unsigned r = x + 0x7FFFu + ((x >> 16) & 1u);
    return (unsigned short)(r >> 16);
}
__device__ __forceinline__ float bf16_to_f(unsigned short h) {
    return __uint_as_float(((unsigned)h) << 16);
}
__device__ __forceinline__ void cvt_hl(float v, unsigned short& h, unsigned short& l) {
    h = bf16_rn(v);
    l = bf16_rn(v - bf16_to_f(h));
}

// ---------------- Wt prep: Wt_h/Wt_l[1024 rc][448 k] bf16 ----------------
__global__ void prep_wt(const float* __restrict__ W_ih, const float* __restrict__ W_hh,
                        unsigned short* __restrict__ Wt_h, unsigned short* __restrict__ Wt_l) {
    int rc = blockIdx.x;
    int hj = rc >> 7, lc = rc & 127;
    int gcol = (lc >> 5) * 256 + hj * 32 + (lc & 31);
    for (int k = threadIdx.x; k < 448; k += 256) {
        float v = 0.f;
        if (k < 175) v = W_ih[(size_t)k * 1024 + gcol];
        else if (k >= 176 && k < 432) v = W_hh[(size_t)(k - 176) * 1024 + gcol];
        unsigned short h, l; cvt_hl(v, h, l);
        Wt_h[(size_t)rc * 448 + k] = h;
        Wt_l[(size_t)rc * 448 + k] = l;
    }
}

// ---------------- Wt_o prep: [128 rc = hj*16+c][256 k] bf16 h/l ----------------
__global__ void prep_wo(const float* __restrict__ W_out,
                        unsigned short* __restrict__ Wt_oh, unsigned short* __restrict__ Wt_ol) {
    int rc = blockIdx.x;
    int hj = rc >> 4, c = rc & 15;
    int col = (c < 12) ? (hj * 12 + c) : (c < 14 ? 76 + c : 999);
    for (int k = threadIdx.x; k < 256; k += 256) {
        float v = (col < 90) ? W_out[(size_t)k * 90 + col] : 0.f;
        unsigned short h, l; cvt_hl(v, h, l);
        Wt_oh[(size_t)rc * 256 + k] = h;
        Wt_ol[(size_t)rc * 256 + k] = l;
    }
}

// ---------------- Encoder -> xin_h[t][b][176] bf16 (32-batch, 3 blocks/CU) ----
__global__ __launch_bounds__(256, 3) void enc_kernel(
    const float* __restrict__ coords,
    const float* __restrict__ W_e1, const float* __restrict__ b_e1,
    const float* __restrict__ W_e2, const float* __restrict__ b_e2,
    unsigned short* __restrict__ xin_h)
{
    __shared__ float C[32][45];              // only the 44 used cols
    __shared__ float H[32][2][65];
    __shared__ float W2[64][64];
    __shared__ unsigned short O16[128][34];  // bf16 (exact: output is bf16-rounded anyway)

    int t  = blockIdx.x >> 5;
    int bc = blockIdx.x & 31;
    int tid = threadIdx.x;

    for (int idx = tid; idx < 32 * 44; idx += 256) {
        int bl = idx / 44, j = idx - bl * 44;
        C[bl][j] = coords[((size_t)(bc * 32 + bl) * SEQ + t) * 88 + (j >> 1) * 4 + (j & 1)];
    }
    for (int idx = tid; idx < 64 * 64; idx += 256)
        W2[idx >> 6][idx & 63] = W_e2[idx];
    __syncthreads();

    {   // phase A
        int b  = tid >> 3;
        int cq = (tid & 7) * 8;
        float w0[8], w1[8], bb[8];
#pragma unroll
        for (int c = 0; c < 8; c++) { w0[c] = W_e1[cq + c]; w1[c] = W_e1[64 + cq + c]; bb[c] = b_e1[cq + c]; }
        for (int tm = 0; tm < 2; tm++) {
            float acc[8];
#pragma unroll
            for (int c = 0; c < 8; c++) acc[c] = 0.f;
            for (int p = 0; p < 11; p++) {
                float x = C[b][tm * 22 + p * 2];
                float y = C[b][tm * 22 + p * 2 + 1];
#pragma unroll
                for (int c = 0; c < 8; c++) {
                    float h = fmaf(x, w0[c], fmaf(y, w1[c], bb[c]));
                    acc[c] += fmaxf(h, 0.f);
                }
            }
#pragma unroll
            for (int c = 0; c < 8; c++) H[b][tm][cq + c] = acc[c] * (1.0f / 11.0f);
        }
    }
    __syncthreads();

    {   // phase B
        int b  = tid >> 3;
        int tm = (tid >> 2) & 1;
        int ch = (tid & 3) * 16;
        float acc[16];
#pragma unroll
        for (int c = 0; c < 16; c++) acc[c] = 0.f;
        for (int k = 0; k < 64; k++) {
            float h = H[b][tm][k];
#pragma unroll
            for (int c = 0; c < 16; c++) acc[c] = fmaf(h, W2[k][ch + c], acc[c]);
        }
#pragma unroll
        for (int c = 0; c < 16; c++)
            O16[tm * 64 + ch + c][b] = bf16_rn(acc[c] + b_e2[ch + c]);
    }
    __syncthreads();

    unsigned short* xrow = xin_h + ((size_t)t * 1024 + bc * 32) * 176;
    for (int idx = tid; idx < 32 * 22; idx += 256) {
        int bl = idx / 22, oct = idx - bl * 22;
        unsigned short hs[8];
#pragma unroll
        for (int e = 0; e < 8; e++) {
            int k = oct * 8 + e;
            if (k < 44)       hs[e] = bf16_rn(C[bl][k]);
            else if (k < 172) hs[e] = O16[k - 44][bl];
            else              hs[e] = 0;
        }
        uint4 pk;
        pk.x = (unsigned)hs[0] | ((unsigned)hs[1] << 16);
        pk.y = (unsigned)hs[2] | ((unsigned)hs[3] << 16);
        pk.z = (unsigned)hs[4] | ((unsigned)hs[5] << 16);
        pk.w = (unsigned)hs[6] | ((unsigned)hs[7] << 16);
        *(uint4*)(xrow + (size_t)bl * 176 + oct * 8) = pk;
    }
}

#define MFMA_B(d, a, b) d = __builtin_amdgcn_mfma_f32_16x16x32_bf16(a, b, d, 0, 0, 0)

#define P_LOAD(R0, R1, R2, R3, KO) \
    R0 = *(const uint4*)(wbh + (size_t)c0 * 448 + (KO) + oct * 8); \
    R1 = *(const uint4*)(wbl + (size_t)c0 * 448 + (KO) + oct * 8); \
    R2 = *(const uint4*)(wbh + (size_t)c1 * 448 + (KO) + oct * 8); \
    R3 = *(const uint4*)(wbl + (size_t)c1 * 448 + (KO) + oct * 8);

#define P_STORE(R0, R1, R2, R3, NB) \
    *(uint4*)&BB[NB][0][c0 * 40 + oct * 8] = R0; \
    *(uint4*)&BB[NB][1][c0 * 40 + oct * 8] = R1; \
    *(uint4*)&BB[NB][0][c1 * 40 + oct * 8] = R2; \
    *(uint4*)&BB[NB][1][c1 * 40 + oct * 8] = R3;

// ---------------- Per-step kernel (round-7 proven, byte-identical) ----------
// grid 256 x 512 threads: waves 0-3 compute (out-MFMA + gates K-loop),
// waves 4-7 stage B chunks, 3-buffer rotation, loads issued 2 segments early.
// Per-step launches: kernel-boundary coherence is the only mechanism proven
// reliable for the cross-block hx exchange (rounds 8/9 failed with in-kernel
// fence+barrier schemes).
__global__ __launch_bounds__(512, 1) void step_kernel(
    int t,
    const unsigned short* __restrict__ xin_h,
    const unsigned short* __restrict__ hxh_in, const unsigned short* __restrict__ hxl_in,
    unsigned short* __restrict__ hxh_out, unsigned short* __restrict__ hxl_out,
    float* __restrict__ cx,
    const unsigned short* __restrict__ Wt_h, const unsigned short* __restrict__ Wt_l,
    const unsigned short* __restrict__ Wt_oh, const unsigned short* __restrict__ Wt_ol,
    const float* __restrict__ b_ih, const float* __restrict__ b_hh,
    const float* __restrict__ b_out,
    const float* __restrict__ pitch, float* __restrict__ d_out)
{
    __shared__ unsigned short AH[32 * 456];        // 29184 B
    __shared__ unsigned short AL[32 * 456];        // 29184 B
    __shared__ unsigned short BB[3][2][128 * 40];  // 61440 B
    __shared__ float U[128 * 33];                  // 16896 B: out partials / G gates
    __shared__ float predL[32][2];                 // 256 B

    int tid = threadIdx.x;
    int bi = blockIdx.x & 31, hj = blockIdx.x >> 5;
    int bg0 = bi * 32;
    int l = tid & 63, w = (tid >> 6) & 3;
    int lr = l & 15, qa = l >> 4;

    const unsigned short* wbh = Wt_h + (size_t)(hj * 128) * 448;
    const unsigned short* wbl = Wt_l + (size_t)(hj * 128) * 448;

    // ---- stage ----
    for (int idx = tid; idx < 32 * 32; idx += 512) {   // hx rows 176..431 (always)
        int b = idx >> 5, oct = idx & 31;
        *(uint4*)&AH[b * 456 + 176 + oct * 8] =
            *(const uint4*)(hxh_in + (size_t)(bg0 + b) * 256 + oct * 8);
        *(uint4*)&AL[b * 456 + 176 + oct * 8] =
            *(const uint4*)(hxl_in + (size_t)(bg0 + b) * 256 + oct * 8);
    }
    if (t < SEQ) {
        const unsigned short* xr = xin_h + ((size_t)t * 1024 + bg0) * 176;
        for (int idx = tid; idx < 32 * 22; idx += 512) {     // x rows 0..175
            int b = idx / 22, oct = idx - b * 22;
            *(uint4*)&AH[b * 456 + oct * 8] = *(const uint4*)(xr + (size_t)b * 176 + oct * 8);
        }
        if (tid < 64) {   // AL k160..175 zero; AH/AL tails k432..447 zero
            int b = tid >> 1, h8 = (tid & 1) * 8;
            *(uint4*)&AL[b * 456 + 160 + h8] = make_uint4(0, 0, 0, 0);
            *(uint4*)&AH[b * 456 + 432 + h8] = make_uint4(0, 0, 0, 0);
            *(uint4*)&AL[b * 456 + 432 + h8] = make_uint4(0, 0, 0, 0);
        }
        {   // BB chunk 0
            int c = tid >> 2, o = tid & 3;
            *(uint4*)&BB[0][0][c * 40 + o * 8] = *(const uint4*)(wbh + (size_t)c * 448 + o * 8);
            *(uint4*)&BB[0][1][c * 40 + o * 8] = *(const uint4*)(wbl + (size_t)c * 448 + o * 8);
        }
    }
    __syncthreads();   // B1

    // ---- out-MFMA (waves 0-3) / producer prologue loads (waves 4-7) ----
    uint4 rA0, rA1, rA2, rA3, rB0, rB1, rB2, rB3;
    int c0 = (tid & 255) >> 2, oct = tid & 3, c1 = ((tid & 255) >> 2) + 64;
    if (tid < 256) {
        const unsigned short* woh = Wt_oh + ((size_t)(hj * 16 + lr)) * 256 + w * 64 + qa * 8;
        const unsigned short* wol = Wt_ol + ((size_t)(hj * 16 + lr)) * 256 + w * 64 + qa * 8;
        bf16x8 bh0 = *(const bf16x8*)(woh);
        bf16x8 bl0 = *(const bf16x8*)(wol);
        bf16x8 bh1 = *(const bf16x8*)(woh + 32);
        bf16x8 bl1 = *(const bf16x8*)(wol + 32);
        f32x4 acce[2];
        acce[0] = (f32x4){0.f, 0.f, 0.f, 0.f};
        acce[1] = (f32x4){0.f, 0.f, 0.f, 0.f};
#pragma unroll
        for (int ks2 = 0; ks2 < 2; ks2++) {
            bf16x8 bh = ks2 ? bh1 : bh0;
            bf16x8 bl = ks2 ? bl1 : bl0;
#pragma unroll
            for (int mt = 0; mt < 2; mt++) {
                bf16x8 ah = *(const bf16x8*)&AH[(mt * 16 + lr) * 456 + 176 + w * 64 + ks2 * 32 + qa * 8];
                bf16x8 al = *(const bf16x8*)&AL[(mt * 16 + lr) * 456 + 176 + w * 64 + ks2 * 32 + qa * 8];
                MFMA_B(acce[mt], ah, bh);
                MFMA_B(acce[mt], ah, bl);
                MFMA_B(acce[mt], al, bh);
            }
        }
#pragma unroll
        for (int mt = 0; mt < 2; mt++)
#pragma unroll
            for (int r = 0; r < 4; r++)
                U[w * 512 + (mt * 16 + qa * 4 + r) * 16 + lr] = acce[mt][r];
    } else if (t < SEQ) {
        P_LOAD(rA0, rA1, rA2, rA3, 32)    // chunk 1
        P_LOAD(rB0, rB1, rB2, rB3, 64)    // chunk 2
    }
    __syncthreads();   // B2

    // ---- reduce partials; write out_{t-1}; pred -> predL ----
    if (tid < 256) {
#pragma unroll
        for (int j = 0; j < 2; j++) {
            int i = tid * 2 + j;
            int b = i >> 4, c = i & 15;
            float v = U[i] + U[512 + i] + U[1024 + i] + U[1536 + i];
            if (c < 14) {
                int col = (c < 12) ? (hj * 12 + c) : (76 + c);
                if (col < 90) {
                    if (t > 0) {
                        float vv = (v + b_out[col]) * pitch[c & 1];
                        if (c < 12) d_out[((size_t)(bg0 + b) * SEQ + (t - 1)) * 90 + col] = vv;
                        else predL[b][c - 12] = vv;
                    } else if (c >= 12) {
                        predL[b][c - 12] = 0.f;
                    }
                }
            }
        }
    }
    __syncthreads();   // B3

    if (t < SEQ) {
        // ---- closest distance; fill A rows 172..174 ----
        if (tid < 32) {
            int b = tid;
            float p0 = predL[b][0], p1 = predL[b][1];
            float m = 1e30f;
#pragma unroll
            for (int p = 0; p < 22; p++) {
                float px = bf16_to_f(AH[b * 456 + 2 * p]);
                float py = bf16_to_f(AH[b * 456 + 2 * p + 1]);
                float dx = p0 - px, dy = p1 - py;
                m = fminf(m, fmaf(dx, dx, dy * dy));
            }
            unsigned short h, lo;
            cvt_hl(sqrtf(m), h, lo); AH[b * 456 + 172] = h; AL[b * 456 + 172] = lo;
            cvt_hl(p0, h, lo);       AH[b * 456 + 173] = h; AL[b * 456 + 173] = lo;
            cvt_hl(p1, h, lo);       AH[b * 456 + 174] = h; AL[b * 456 + 174] = lo;
        }
        __syncthreads();   // B4

        if (tid < 256) {
            // ---- consumer K-loop: 14 x K=32, fully unrolled, 3-buf ----
            f32x4 acc[2][2];
#pragma unroll
            for (int ct = 0; ct < 2; ct++)
#pragma unroll
                for (int mt = 0; mt < 2; mt++) acc[ct][mt] = (f32x4){0.f, 0.f, 0.f, 0.f};

#pragma unroll
            for (int ks = 0; ks < 14; ks++) {
                const int cur = ks % 3;
                bf16x8 ah[2], al[2], bh[2], bl[2];
#pragma unroll
                for (int mt = 0; mt < 2; mt++)
                    ah[mt] = *(const bf16x8*)&AH[(mt * 16 + lr) * 456 + ks * 32 + qa * 8];
                if (ks >= 5) {
#pragma unroll
                    for (int mt = 0; mt < 2; mt++)
                        al[mt] = *(const bf16x8*)&AL[(mt * 16 + lr) * 456 + ks * 32 + qa * 8];
                }
#pragma unroll
                for (int ct = 0; ct < 2; ct++) {
                    bh[ct] = *(const bf16x8*)&BB[cur][0][(w * 32 + ct * 16 + lr) * 40 + qa * 8];
                    bl[ct] = *(const bf16x8*)&BB[cur][1][(w * 32 + ct * 16 + lr) * 40 + qa * 8];
                }
#pragma unroll
                for (int ct = 0; ct < 2; ct++)
#pragma unroll
                    for (int mt = 0; mt < 2; mt++) {
                        MFMA_B(acc[ct][mt], ah[mt], bh[ct]);
                        MFMA_B(acc[ct][mt], ah[mt], bl[ct]);
                        if (ks >= 5) MFMA_B(acc[ct][mt], al[mt], bh[ct]);
                    }
                __syncthreads();
            }

            // ---- G exchange ----
#pragma unroll
            for (int ct = 0; ct < 2; ct++)
#pragma unroll
                for (int mt = 0; mt < 2; mt++)
#pragma unroll
                    for (int r = 0; r < 4; r++)
                        U[(w * 32 + ct * 16 + lr) * 33 + (mt * 16 + qa * 4 + r)] = acc[ct][mt][r];
        } else {
            // ---- producer loop: store chunk ks+1 (loaded 2 iters ago), issue ks+3 ----
#pragma unroll
            for (int ks = 0; ks < 14; ks++) {
                if (ks <= 12) {
                    const int nb = (ks + 1) % 3;
                    if ((ks & 1) == 0) { P_STORE(rA0, rA1, rA2, rA3, nb) }
                    else               { P_STORE(rB0, rB1, rB2, rB3, nb) }
                }
                if (ks <= 10) {
                    const int ko = (ks + 3) * 32;
                    if ((ks & 1) == 0) { P_LOAD(rA0, rA1, rA2, rA3, ko) }
                    else               { P_LOAD(rB0, rB1, rB2, rB3, ko) }
                }
                __syncthreads();
            }
        }
        __syncthreads();   // B5

        // ---- LSTM pointwise ----
        if (tid < 256) {
            int b = tid & 31, hq = tid >> 5;
            unsigned short hh[4], hl[4];
#pragma unroll
            for (int q = 0; q < 4; q++) {
                int hlc = hq * 4 + q;
                int gb = hj * 32 + hlc;
                float iv = U[(0 * 32 + hlc) * 33 + b] + b_ih[gb]        + b_hh[gb];
                float fv = U[(1 * 32 + hlc) * 33 + b] + b_ih[256 + gb]  + b_hh[256 + gb];
                float gv = U[(2 * 32 + hlc) * 33 + b] + b_ih[512 + gb]  + b_hh[512 + gb];
                float ov = U[(3 * 32 + hlc) * 33 + b] + b_ih[768 + gb]  + b_hh[768 + gb];
                size_t cidx = (size_t)gb * 1024 + bg0 + b;
                float c_old = cx[cidx];
                float c_new = fmaf(sigmoidf_(fv), c_old, sigmoidf_(iv) * tanhf(gv));
                cx[cidx] = c_new;
                float hv = sigmoidf_(ov) * tanhf(c_new);
                cvt_hl(hv, hh[q], hl[q]);
            }
            size_t ho = (size_t)(bg0 + b) * 256 + hj * 32 + hq * 4;
            *(ushort4*)&hxh_out[ho] = make_ushort4(hh[0], hh[1], hh[2], hh[3]);
            *(ushort4*)&hxl_out[ho] = make_ushort4(hl[0], hl[1], hl[2], hl[3]);
        }
    }
}

extern "C" void kernel_launch(void* const* d_in, const int* in_sizes, int n_in,
                              void* d_out, int out_size, void* d_ws, size_t ws_size,
                              hipStream_t stream) {
    const float* coords = (const float*)d_in[0];
    const float* pitch  = (const float*)d_in[1];
    const float* W_e1   = (const float*)d_in[2];
    const float* b_e1   = (const float*)d_in[3];
    const float* W_e2   = (const float*)d_in[4];
    const float* b_e2   = (const float*)d_in[5];
    const float* W_ih   = (const float*)d_in[6];
    const float* b_ih   = (const float*)d_in[7];
    const float* W_hh   = (const float*)d_in[8];
    const float* b_hh   = (const float*)d_in[9];
    const float* W_out  = (const float*)d_in[10];
    const float* b_out  = (const float*)d_in[11];
    float* out = (float*)d_out;
    float* ws  = (float*)d_ws;

    // ws layout (float offsets); total ~19.3M floats ~= 77 MB
    float* cxb = ws;                                          // 262144
    unsigned short* hxhA = (unsigned short*)(ws + 262144);    // 131072 f
    unsigned short* hxlA = (unsigned short*)(ws + 393216);    // 131072 f
    unsigned short* hxhB = (unsigned short*)(ws + 524288);    // 131072 f
    unsigned short* hxlB = (unsigned short*)(ws + 655360);    // 131072 f
    unsigned short* Wt_h = (unsigned short*)(ws + 786432);    // 229376 f
    unsigned short* Wt_l = (unsigned short*)(ws + 1015808);   // 229376 f
    unsigned short* Wt_oh = (unsigned short*)(ws + 1245184);  // 16384 f
    unsigned short* Wt_ol = (unsigned short*)(ws + 1261568);  // 16384 f
    unsigned short* xin_h = (unsigned short*)(ws + 1277952);  // 18022400 f

    // zero cx + hxhA + hxlA (poisoned 0xAA by harness)
    hipMemsetAsync(ws, 0, (size_t)524288 * sizeof(float), stream);

    prep_wt<<<1024, 256, 0, stream>>>(W_ih, W_hh, Wt_h, Wt_l);
    prep_wo<<<128, 256, 0, stream>>>(W_out, Wt_oh, Wt_ol);
    enc_kernel<<<SEQ * 32, 256, 0, stream>>>(coords, W_e1, b_e1, W_e2, b_e2, xin_h);

    for (int t = 0; t <= SEQ; t++) {
        bool even = !(t & 1);
        step_kernel<<<256, 512, 0, stream>>>(
            t, xin_h,
            even ? hxhA : hxhB, even ? hxlA : hxlB,
            even ? hxhB : hxhA, even ? hxlB : hxlA,
            cxb, Wt_h, Wt_l, Wt_oh, Wt_ol, b_ih, b_hh, b_out, pitch, out);
    }
}